// Round 10
// baseline (289.659 us; speedup 1.0000x reference)
//
#include <hip/hip_runtime.h>
#include <hip/hip_bf16.h>
#include <hip/hip_cooperative_groups.h>

namespace cg = cooperative_groups;

#define B 2
#define S 2048
#define E 1024
#define H 16
#define D 64

typedef unsigned short ushort_t;
typedef __attribute__((ext_vector_type(8))) short bf16x8;    // 8 bf16 = 4 VGPRs
typedef __attribute__((ext_vector_type(4))) float f32x4;     // 16x16 C/D frag
typedef __attribute__((ext_vector_type(16))) float f32x16;   // 32x32 C/D frag

static __device__ __forceinline__ ushort_t f2bf(float f) {
    union { float f; unsigned u; } v; v.f = f;
    unsigned r = v.u + 0x7fffu + ((v.u >> 16) & 1u);   // RNE
    return (ushort_t)(r >> 16);
}

#define MFMA(a, b, c)   __builtin_amdgcn_mfma_f32_16x16x32_bf16((a), (b), (c), 0, 0, 0)
#define MFMA32(a, b, c) __builtin_amdgcn_mfma_f32_32x32x16_bf16((a), (b), (c), 0, 0, 0)
#define PACKBF(hi, lo) __builtin_amdgcn_perm((hi), (lo), 0x07060302u)
#define WQSCALE 0.18033688011112042f   // 0.125 * log2(e)
// LDS-only barrier: waits ds ops, leaves global prefetch loads in flight.
#define LBAR() do { asm volatile("s_waitcnt lgkmcnt(0)" ::: "memory"); \
                    __builtin_amdgcn_s_barrier(); } while (0)

// ================= Fused cooperative kernel: qkv -> flash -> out_proj =================
// 512 blocks x 512 threads, 2 blocks/CU co-resident (73,728 B LDS, <=128 VGPR).
// Phase 1 and 2 share the XCD-locality mapping (lin&7 = xcd, 4 bh per XCD), so
// q/k/vT are produced AND consumed within one XCD's L2. grid.sync() between
// phases replaces two kernel launches (~10 us gap each).
__global__ __launch_bounds__(512, 4) void fused_all(
    const float* __restrict__ x,
    const float* __restrict__ Wq, const float* __restrict__ Wk, const float* __restrict__ Wv,
    const float* __restrict__ Wo, const float* __restrict__ bo,
    ushort_t* __restrict__ q, ushort_t* __restrict__ k, ushort_t* __restrict__ vT,
    ushort_t* __restrict__ ao, ushort_t* __restrict__ wob, float* __restrict__ Y)
{
    __shared__ char smem[73728];
    cg::grid_group grid = cg::this_grid();
    int th = threadIdx.x;
    int lin = blockIdx.x;                   // 512 blocks
    int xcd = lin & 7, loc = lin >> 3;      // XCD round-robin %8
    int bh = xcd * 4 + (loc >> 4);          // 4 bh per XCD
    int b = bh >> 4, h = bh & 15;

    // ---------------- Phase 1: QKV projection (two 64-row s-tiles per block) ----------------
    {
        ushort_t (*Xs)[64][72] = (ushort_t (*)[64][72])smem;           // 2 x 9,216 B
        ushort_t (*Wqs)[72] = (ushort_t (*)[72])(smem + 18432);
        ushort_t (*Wks)[72] = (ushort_t (*)[72])(smem + 27648);
        ushort_t (*Wvs)[72] = (ushort_t (*)[72])(smem + 36864);        // total 46,080 B
        int hhalf = th >> 8, t = th & 255;
        int s0 = (loc & 15) * 128 + hhalf * 64;

        {   // fused Wo fp32 -> bf16 (512 blocks x 2048 elems = 1M)
            int i = lin * 2048 + th * 4;
            float4 f = *(const float4*)(Wo + i);
            ushort4 u2; u2.x = f2bf(f.x); u2.y = f2bf(f.y); u2.z = f2bf(f.z); u2.w = f2bf(f.w);
            *(ushort4*)(wob + i) = u2;
        }
        {   // stage x (64 s x 64 d per half) fp32 -> bf16
            int i = t >> 2, d0 = (t & 3) * 16;
            const float* xp = x + ((size_t)(b * S + s0 + i)) * E + h * D + d0;
            #pragma unroll
            for (int c = 0; c < 16; c += 4) {
                float4 f = *(const float4*)(xp + c);
                Xs[hhalf][i][d0 + c + 0] = f2bf(f.x); Xs[hhalf][i][d0 + c + 1] = f2bf(f.y);
                Xs[hhalf][i][d0 + c + 2] = f2bf(f.z); Xs[hhalf][i][d0 + c + 3] = f2bf(f.w);
            }
        }
        {   // stage weights once per block (all 512 threads, 8 elems/matrix each)
            int rw = th >> 3, c8 = (th & 7) * 8;
            const float* wqp = Wq + rw * 64 + c8;
            const float* wkp = Wk + rw * 64 + c8;
            const float* wvp = Wv + rw * 64 + c8;
            float4 f0 = *(const float4*)(wqp), f1 = *(const float4*)(wqp + 4);
            Wqs[rw][c8 + 0] = f2bf(f0.x * WQSCALE); Wqs[rw][c8 + 1] = f2bf(f0.y * WQSCALE);
            Wqs[rw][c8 + 2] = f2bf(f0.z * WQSCALE); Wqs[rw][c8 + 3] = f2bf(f0.w * WQSCALE);
            Wqs[rw][c8 + 4] = f2bf(f1.x * WQSCALE); Wqs[rw][c8 + 5] = f2bf(f1.y * WQSCALE);
            Wqs[rw][c8 + 6] = f2bf(f1.z * WQSCALE); Wqs[rw][c8 + 7] = f2bf(f1.w * WQSCALE);
            f0 = *(const float4*)(wkp); f1 = *(const float4*)(wkp + 4);
            Wks[rw][c8 + 0] = f2bf(f0.x); Wks[rw][c8 + 1] = f2bf(f0.y);
            Wks[rw][c8 + 2] = f2bf(f0.z); Wks[rw][c8 + 3] = f2bf(f0.w);
            Wks[rw][c8 + 4] = f2bf(f1.x); Wks[rw][c8 + 5] = f2bf(f1.y);
            Wks[rw][c8 + 6] = f2bf(f1.z); Wks[rw][c8 + 7] = f2bf(f1.w);
            f0 = *(const float4*)(wvp); f1 = *(const float4*)(wvp + 4);
            Wvs[rw][c8 + 0] = f2bf(f0.x); Wvs[rw][c8 + 1] = f2bf(f0.y);
            Wvs[rw][c8 + 2] = f2bf(f0.z); Wvs[rw][c8 + 3] = f2bf(f0.w);
            Wvs[rw][c8 + 4] = f2bf(f1.x); Wvs[rw][c8 + 5] = f2bf(f1.y);
            Wvs[rw][c8 + 6] = f2bf(f1.z); Wvs[rw][c8 + 7] = f2bf(f1.w);
        }
        __syncthreads();

        int w = (th >> 6) & 3, lane = th & 63, m = lane & 15, quad = lane >> 4;
        bf16x8 a0 = *(bf16x8*)&Xs[hhalf][16 * w + m][quad * 8];
        bf16x8 a1 = *(bf16x8*)&Xs[hhalf][16 * w + m][32 + quad * 8];
        f32x4 cq[4], ck[4], cv[4];
        #pragma unroll
        for (int nt = 0; nt < 4; nt++) { cq[nt] = (f32x4)0.f; ck[nt] = (f32x4)0.f; cv[nt] = (f32x4)0.f; }
        #pragma unroll
        for (int nt = 0; nt < 4; nt++) {
            bf16x8 b0, b1;
            b0 = *(bf16x8*)&Wqs[nt * 16 + m][quad * 8]; b1 = *(bf16x8*)&Wqs[nt * 16 + m][32 + quad * 8];
            cq[nt] = MFMA(a0, b0, cq[nt]); cq[nt] = MFMA(a1, b1, cq[nt]);
            b0 = *(bf16x8*)&Wks[nt * 16 + m][quad * 8]; b1 = *(bf16x8*)&Wks[nt * 16 + m][32 + quad * 8];
            ck[nt] = MFMA(a0, b0, ck[nt]); ck[nt] = MFMA(a1, b1, ck[nt]);
            b0 = *(bf16x8*)&Wvs[nt * 16 + m][quad * 8]; b1 = *(bf16x8*)&Wvs[nt * 16 + m][32 + quad * 8];
            cv[nt] = MFMA(a0, b0, cv[nt]); cv[nt] = MFMA(a1, b1, cv[nt]);
        }
        size_t base = (size_t)bh * S + s0;
        #pragma unroll
        for (int nt = 0; nt < 4; nt++)
            #pragma unroll
            for (int r = 0; r < 4; r++) {
                size_t idx = (base + 16 * w + quad * 4 + r) * D + nt * 16 + m;
                q[idx] = f2bf(cq[nt][r]);
                k[idx] = f2bf(ck[nt][r]);
            }
        // v transpose via Xs[hhalf] (dead after A-frag loads), coalesced write to vT
        __syncthreads();
        #pragma unroll
        for (int nt = 0; nt < 4; nt++)
            #pragma unroll
            for (int r = 0; r < 4; r++)
                Xs[hhalf][nt * 16 + m][16 * w + quad * 4 + r] = f2bf(cv[nt][r]);
        __syncthreads();
        {
            int d0 = t >> 2, sc = (t & 3) * 16;
            ushort_t* vp = vT + ((size_t)bh * D + d0) * S + s0 + sc;
            *(bf16x8*)(vp)     = *(bf16x8*)&Xs[hhalf][d0][sc];
            *(bf16x8*)(vp + 8) = *(bf16x8*)&Xs[hhalf][d0][sc + 8];
        }
    }
    grid.sync();

    // ---------------- Phase 2: flash attention (R17 structure) ----------------
    {
        ushort_t (*Ks)[2][64][72] = (ushort_t (*)[2][64][72])smem;            // 36,864 B
        ushort_t (*Vt)[2][64][72] = (ushort_t (*)[2][64][72])(smem + 36864);  // 36,864 B
        int t = th;
        int q0 = (loc & 15) * 128;
        int w = t >> 6, lane = t & 63, l31 = lane & 31, half = lane >> 5;
        int g = w >> 2, wqw = w & 3;
        int tg = t & 255;

        const ushort_t* qb = q + ((size_t)bh * S + q0) * D;
        const ushort_t* kb = k + (size_t)bh * S * D;
        const ushort_t* vb = vT + (size_t)bh * D * S;

        bf16x8 qf[4];
        {
            const ushort_t* qp = qb + (size_t)(wqw * 32 + l31) * D + half * 8;
            #pragma unroll
            for (int c = 0; c < 4; c++) qf[c] = *(const bf16x8*)(qp + c * 16);
        }

        f32x16 o0 = (f32x16)0.f, o1 = (f32x16)0.f;
        float2 ls2 = make_float2(0.f, 0.f);

        int sr = tg >> 2, scc = (tg & 3) * 16;
        bf16x8 kp0, kp1, vp0, vp1;

        {
            int k00 = g * 64;
            const ushort_t* kp = kb + (size_t)(k00 + sr) * D + scc;
            const ushort_t* vp = vb + (size_t)sr * S + k00 + scc;
            kp0 = *(const bf16x8*)(kp);     kp1 = *(const bf16x8*)(kp + 8);
            vp0 = *(const bf16x8*)(vp);     vp1 = *(const bf16x8*)(vp + 8);
            *(bf16x8*)&Ks[g][0][sr][scc]     = kp0;
            *(bf16x8*)&Ks[g][0][sr][scc + 8] = kp1;
            *(bf16x8*)&Vt[g][0][sr][scc]     = vp0;
            *(bf16x8*)&Vt[g][0][sr][scc + 8] = vp1;
        }
        LBAR();
        {
            int k01 = (2 + g) * 64;
            const ushort_t* kp = kb + (size_t)(k01 + sr) * D + scc;
            const ushort_t* vp = vb + (size_t)sr * S + k01 + scc;
            kp0 = *(const bf16x8*)(kp);     kp1 = *(const bf16x8*)(kp + 8);
            vp0 = *(const bf16x8*)(vp);     vp1 = *(const bf16x8*)(vp + 8);
        }

        const int NJ = S / 128;
        for (int jt = 0; jt < NJ; jt++) {
            int p = jt & 1;
            if (jt + 1 < NJ) {
                *(bf16x8*)&Ks[g][1 - p][sr][scc]     = kp0;
                *(bf16x8*)&Ks[g][1 - p][sr][scc + 8] = kp1;
                *(bf16x8*)&Vt[g][1 - p][sr][scc]     = vp0;
                *(bf16x8*)&Vt[g][1 - p][sr][scc + 8] = vp1;
            }
            if (jt + 2 < NJ) {
                int k0n = (2 * (jt + 2) + g) * 64;
                const ushort_t* kp = kb + (size_t)(k0n + sr) * D + scc;
                const ushort_t* vp = vb + (size_t)sr * S + k0n + scc;
                kp0 = *(const bf16x8*)(kp);     kp1 = *(const bf16x8*)(kp + 8);
                vp0 = *(const bf16x8*)(vp);     vp1 = *(const bf16x8*)(vp + 8);
            }

            union { unsigned u[4]; bf16x8 v; } pa[4];
            #pragma unroll
            for (int st = 0; st < 2; st++) {
                f32x16 e = (f32x16)0.f;
                __builtin_amdgcn_s_setprio(1);
                #pragma unroll
                for (int c = 0; c < 4; c++) {
                    bf16x8 ka = *(bf16x8*)&Ks[g][p][st * 32 + l31][c * 16 + half * 8];
                    e = MFMA32(ka, qf[c], e);
                }
                __builtin_amdgcn_s_setprio(0);
                unsigned pt[16];
                #pragma unroll
                for (int r = 0; r < 16; r += 2) {
                    float pe0 = __builtin_amdgcn_exp2f(e[r]);
                    float pe1 = __builtin_amdgcn_exp2f(e[r + 1]);
                    ls2.x += pe0; ls2.y += pe1;
                    pt[r]     = __float_as_uint(pe0);
                    pt[r + 1] = __float_as_uint(pe1);
                }
                #pragma unroll
                for (int c2 = 0; c2 < 2; c2++) {
                    int rb = c2 * 8;
                    unsigned dA = PACKBF(pt[rb + 1], pt[rb + 0]);
                    unsigned dB = PACKBF(pt[rb + 3], pt[rb + 2]);
                    unsigned dC = PACKBF(pt[rb + 5], pt[rb + 4]);
                    unsigned dD = PACKBF(pt[rb + 7], pt[rb + 6]);
                    asm volatile("v_permlane32_swap_b32 %0, %1" : "+v"(dA), "+v"(dC));
                    asm volatile("v_permlane32_swap_b32 %0, %1" : "+v"(dB), "+v"(dD));
                    int kc = st * 2 + c2;
                    pa[kc].u[0] = dA;
                    pa[kc].u[1] = dB;
                    pa[kc].u[2] = dC;
                    pa[kc].u[3] = dD;
                }
            }

            __builtin_amdgcn_s_setprio(1);
            #pragma unroll
            for (int kc = 0; kc < 4; kc++) {
                bf16x8 vf0 = *(bf16x8*)&Vt[g][p][l31][kc * 16 + half * 8];
                bf16x8 vf1 = *(bf16x8*)&Vt[g][p][32 + l31][kc * 16 + half * 8];
                o0 = MFMA32(pa[kc].v, vf0, o0);
                o1 = MFMA32(pa[kc].v, vf1, o1);
            }
            __builtin_amdgcn_s_setprio(0);
            LBAR();
        }

        float lsum = ls2.x + ls2.y;
        float* cmb = (float*)smem;
        int slot = (wqw * 64 + lane) * 33;
        if (g == 1) {
            #pragma unroll
            for (int r2 = 0; r2 < 16; r2++) { cmb[slot + r2] = o0[r2]; cmb[slot + 16 + r2] = o1[r2]; }
            cmb[slot + 32] = lsum;
        }
        __syncthreads();
        if (g == 0) {
            #pragma unroll
            for (int r2 = 0; r2 < 16; r2++) { o0[r2] += cmb[slot + r2]; o1[r2] += cmb[slot + 16 + r2]; }
            lsum += cmb[slot + 32];
            float lfull = lsum + __shfl_xor(lsum, 32, 64);
            float inv = 1.001953125f / lfull;
            #pragma unroll
            for (int reg = 0; reg < 16; reg++) {
                int qrow = (reg & 3) + 8 * (reg >> 2) + 4 * half;
                float li = __shfl(inv, qrow, 64);
                int srow = q0 + wqw * 32 + qrow;
                size_t base2 = ((size_t)(b * S + srow)) * E + h * D + l31;
                ao[base2]      = f2bf(o0[reg] * li);
                ao[base2 + 32] = f2bf(o1[reg] * li);
            }
        }
    }
    grid.sync();

    // ---------------- Phase 3: output projection (R17 structure) ----------------
    {
        ushort_t (*As)[128][72] = (ushort_t (*)[128][72])smem;            // 36,864 B
        ushort_t (*Ws)[64][72]  = (ushort_t (*)[64][72])(smem + 36864);   // 18,432 B
        int t = th;
        int swz = (lin & 7) * 64 + (lin >> 3);
        int n0 = (swz & 15) * 64, m0 = (swz >> 4) * 128;
        int w = t >> 6, lane = t & 63, m = lane & 15, quad = lane >> 4;
        f32x4 acc[4];
        #pragma unroll
        for (int nt = 0; nt < 4; nt++) acc[nt] = (f32x4)0.f;

        int ar = t >> 2, ac = (t & 3) * 16;
        int wr = t >> 3, wc = (t & 7) * 8;
        const ushort_t* apb = ao + (size_t)(m0 + ar) * E + ac;
        const ushort_t* wpb = wob + (size_t)(n0 + wr) * E + wc;

        bf16x8 arg[2], wrg;
        {
            *(bf16x8*)&As[0][ar][ac]     = *(const bf16x8*)(apb);
            *(bf16x8*)&As[0][ar][ac + 8] = *(const bf16x8*)(apb + 8);
            *(bf16x8*)&Ws[0][wr][wc]     = *(const bf16x8*)(wpb);
        }
        LBAR();
        {
            arg[0] = *(const bf16x8*)(apb + 64);
            arg[1] = *(const bf16x8*)(apb + 64 + 8);
            wrg    = *(const bf16x8*)(wpb + 64);
        }

        const int KT = E / 64;
        for (int ks = 0; ks < KT; ks++) {
            int p = ks & 1;
            if (ks + 1 < KT) {
                *(bf16x8*)&As[1 - p][ar][ac]     = arg[0];
                *(bf16x8*)&As[1 - p][ar][ac + 8] = arg[1];
                *(bf16x8*)&Ws[1 - p][wr][wc]     = wrg;
            }
            if (ks + 2 < KT) {
                int off = (ks + 2) * 64;
                arg[0] = *(const bf16x8*)(apb + off);
                arg[1] = *(const bf16x8*)(apb + off + 8);
                wrg    = *(const bf16x8*)(wpb + off);
            }
            #pragma unroll
            for (int h2 = 0; h2 < 2; h2++) {
                bf16x8 af = *(bf16x8*)&As[p][w * 16 + m][h2 * 32 + quad * 8];
                #pragma unroll
                for (int nt = 0; nt < 4; nt++) {
                    bf16x8 bfr = *(bf16x8*)&Ws[p][nt * 16 + m][h2 * 32 + quad * 8];
                    acc[nt] = MFMA(af, bfr, acc[nt]);
                }
            }
            LBAR();
        }
        #pragma unroll
        for (int nt = 0; nt < 4; nt++)
            #pragma unroll
            for (int r = 0; r < 4; r++) {
                int row = m0 + w * 16 + quad * 4 + r;
                int col = n0 + nt * 16 + m;
                Y[(size_t)row * E + col] = acc[nt][r] + bo[col];
            }
    }
}

// ================= Fallback kernels (exact R17 path, used if cooperative launch fails) =================
__global__ __launch_bounds__(256) void qkv_proj(
    const float* __restrict__ x,
    const float* __restrict__ Wq, const float* __restrict__ Wk, const float* __restrict__ Wv,
    const float* __restrict__ Wo,
    ushort_t* __restrict__ q, ushort_t* __restrict__ k, ushort_t* __restrict__ vT,
    ushort_t* __restrict__ wob)
{
    __shared__ ushort_t Xs[64][72];
    __shared__ ushort_t Wqs[64][72], Wks[64][72], Wvs[64][72];
    int t = threadIdx.x;
    int bh = blockIdx.y, b = bh >> 4, h = bh & 15;
    int s0 = blockIdx.x * 64;
    {
        int woid = blockIdx.y * 32 + blockIdx.x;
        int i = woid * 1024 + t * 4;
        float4 f = *(const float4*)(Wo + i);
        ushort4 u2; u2.x = f2bf(f.x); u2.y = f2bf(f.y); u2.z = f2bf(f.z); u2.w = f2bf(f.w);
        *(ushort4*)(wob + i) = u2;
    }
    {
        int i = t >> 2, d0 = (t & 3) * 16;
        const float* xp = x + ((size_t)(b * S + s0 + i)) * E + h * D + d0;
        #pragma unroll
        for (int c = 0; c < 16; c += 4) {
            float4 f = *(const float4*)(xp + c);
            Xs[i][d0 + c + 0] = f2bf(f.x); Xs[i][d0 + c + 1] = f2bf(f.y);
            Xs[i][d0 + c + 2] = f2bf(f.z); Xs[i][d0 + c + 3] = f2bf(f.w);
        }
    }
    {
        int e = t >> 2, d0 = (t & 3) * 16;
        const float* wqp = Wq + e * 64 + d0;
        const float* wkp = Wk + e * 64 + d0;
        const float* wvp = Wv + e * 64 + d0;
        #pragma unroll
        for (int c = 0; c < 16; c += 4) {
            float4 fq = *(const float4*)(wqp + c);
            Wqs[e][d0 + c + 0] = f2bf(fq.x * WQSCALE);
            Wqs[e][d0 + c + 1] = f2bf(fq.y * WQSCALE);
            Wqs[e][d0 + c + 2] = f2bf(fq.z * WQSCALE);
            Wqs[e][d0 + c + 3] = f2bf(fq.w * WQSCALE);
            float4 fk = *(const float4*)(wkp + c);
            Wks[e][d0 + c + 0] = f2bf(fk.x); Wks[e][d0 + c + 1] = f2bf(fk.y);
            Wks[e][d0 + c + 2] = f2bf(fk.z); Wks[e][d0 + c + 3] = f2bf(fk.w);
            float4 fv = *(const float4*)(wvp + c);
            Wvs[e][d0 + c + 0] = f2bf(fv.x); Wvs[e][d0 + c + 1] = f2bf(fv.y);
            Wvs[e][d0 + c + 2] = f2bf(fv.z); Wvs[e][d0 + c + 3] = f2bf(fv.w);
        }
    }
    __syncthreads();
    int w = t >> 6, lane = t & 63, m = lane & 15, quad = lane >> 4;
    bf16x8 a0 = *(bf16x8*)&Xs[16 * w + m][quad * 8];
    bf16x8 a1 = *(bf16x8*)&Xs[16 * w + m][32 + quad * 8];
    f32x4 cq[4], ck[4], cv[4];
    #pragma unroll
    for (int nt = 0; nt < 4; nt++) { cq[nt] = (f32x4)0.f; ck[nt] = (f32x4)0.f; cv[nt] = (f32x4)0.f; }
    #pragma unroll
    for (int nt = 0; nt < 4; nt++) {
        bf16x8 b0, b1;
        b0 = *(bf16x8*)&Wqs[nt * 16 + m][quad * 8]; b1 = *(bf16x8*)&Wqs[nt * 16 + m][32 + quad * 8];
        cq[nt] = MFMA(a0, b0, cq[nt]); cq[nt] = MFMA(a1, b1, cq[nt]);
        b0 = *(bf16x8*)&Wks[nt * 16 + m][quad * 8]; b1 = *(bf16x8*)&Wks[nt * 16 + m][32 + quad * 8];
        ck[nt] = MFMA(a0, b0, ck[nt]); ck[nt] = MFMA(a1, b1, ck[nt]);
        b0 = *(bf16x8*)&Wvs[nt * 16 + m][quad * 8]; b1 = *(bf16x8*)&Wvs[nt * 16 + m][32 + quad * 8];
        cv[nt] = MFMA(a0, b0, cv[nt]); cv[nt] = MFMA(a1, b1, cv[nt]);
    }
    size_t base = (size_t)bh * S + s0;
    #pragma unroll
    for (int nt = 0; nt < 4; nt++)
        #pragma unroll
        for (int r = 0; r < 4; r++) {
            size_t idx = (base + 16 * w + quad * 4 + r) * D + nt * 16 + m;
            q[idx] = f2bf(cq[nt][r]);
            k[idx] = f2bf(ck[nt][r]);
        }
    __syncthreads();
    #pragma unroll
    for (int nt = 0; nt < 4; nt++)
        #pragma unroll
        for (int r = 0; r < 4; r++)
            Wvs[nt * 16 + m][16 * w + quad * 4 + r] = f2bf(cv[nt][r]);
    __syncthreads();
    {
        int d0 = t >> 2, sc = (t & 3) * 16;
        ushort_t* vp = vT + ((size_t)bh * D + d0) * S + s0 + sc;
        *(bf16x8*)(vp)     = *(bf16x8*)&Wvs[d0][sc];
        *(bf16x8*)(vp + 8) = *(bf16x8*)&Wvs[d0][sc + 8];
    }
}

__global__ __launch_bounds__(512, 4) void flash_attn(
    const ushort_t* __restrict__ q, const ushort_t* __restrict__ k,
    const ushort_t* __restrict__ vT, ushort_t* __restrict__ ao)
{
    __shared__ ushort_t Ks[2][2][64][72];
    __shared__ ushort_t Vt[2][2][64][72];
    int t = threadIdx.x;
    int lin = blockIdx.x;
    int xcd = lin & 7, loc = lin >> 3;
    int bh = xcd * 4 + (loc >> 4);
    int q0 = (loc & 15) * 128;
    int b = bh >> 4, h = bh & 15;
    int w = t >> 6, lane = t & 63, l31 = lane & 31, half = lane >> 5;
    int g = w >> 2, wqw = w & 3;
    int tg = t & 255;

    const ushort_t* qb = q + ((size_t)bh * S + q0) * D;
    const ushort_t* kb = k + (size_t)bh * S * D;
    const ushort_t* vb = vT + (size_t)bh * D * S;

    bf16x8 qf[4];
    {
        const ushort_t* qp = qb + (size_t)(wqw * 32 + l31) * D + half * 8;
        #pragma unroll
        for (int c = 0; c < 4; c++) qf[c] = *(const bf16x8*)(qp + c * 16);
    }
    f32x16 o0 = (f32x16)0.f, o1 = (f32x16)0.f;
    float2 ls2 = make_float2(0.f, 0.f);
    int sr = tg >> 2, scc = (tg & 3) * 16;
    bf16x8 kp0, kp1, vp0, vp1;
    {
        int k00 = g * 64;
        const ushort_t* kp = kb + (size_t)(k00 + sr) * D + scc;
        const ushort_t* vp = vb + (size_t)sr * S + k00 + scc;
        kp0 = *(const bf16x8*)(kp);     kp1 = *(const bf16x8*)(kp + 8);
        vp0 = *(const bf16x8*)(vp);     vp1 = *(const bf16x8*)(vp + 8);
        *(bf16x8*)&Ks[g][0][sr][scc]     = kp0;
        *(bf16x8*)&Ks[g][0][sr][scc + 8] = kp1;
        *(bf16x8*)&Vt[g][0][sr][scc]     = vp0;
        *(bf16x8*)&Vt[g][0][sr][scc + 8] = vp1;
    }
    LBAR();
    {
        int k01 = (2 + g) * 64;
        const ushort_t* kp = kb + (size_t)(k01 + sr) * D + scc;
        const ushort_t* vp = vb + (size_t)sr * S + k01 + scc;
        kp0 = *(const bf16x8*)(kp);     kp1 = *(const bf16x8*)(kp + 8);
        vp0 = *(const bf16x8*)(vp);     vp1 = *(const bf16x8*)(vp + 8);
    }
    const int NJ = S / 128;
    for (int jt = 0; jt < NJ; jt++) {
        int p = jt & 1;
        if (jt + 1 < NJ) {
            *(bf16x8*)&Ks[g][1 - p][sr][scc]     = kp0;
            *(bf16x8*)&Ks[g][1 - p][sr][scc + 8] = kp1;
            *(bf16x8*)&Vt[g][1 - p][sr][scc]     = vp0;
            *(bf16x8*)&Vt[g][1 - p][sr][scc + 8] = vp1;
        }
        if (jt + 2 < NJ) {
            int k0n = (2 * (jt + 2) + g) * 64;
            const ushort_t* kp = kb + (size_t)(k0n + sr) * D + scc;
            const ushort_t* vp = vb + (size_t)sr * S + k0n + scc;
            kp0 = *(const bf16x8*)(kp);     kp1 = *(const bf16x8*)(kp + 8);
            vp0 = *(const bf16x8*)(vp);     vp1 = *(const bf16x8*)(vp + 8);
        }
        union { unsigned u[4]; bf16x8 v; } pa[4];
        #pragma unroll
        for (int st = 0; st < 2; st++) {
            f32x16 e = (f32x16)0.f;
            __builtin_amdgcn_s_setprio(1);
            #pragma unroll
            for (int c = 0; c < 4; c++) {
                bf16x8 ka = *(bf16x8*)&Ks[g][p][st * 32 + l31][c * 16 + half * 8];
                e = MFMA32(ka, qf[c], e);
            }
            __builtin_amdgcn_s_setprio(0);
            unsigned pt[16];
            #pragma unroll
            for (int r = 0; r < 16; r += 2) {
                float pe0 = __builtin_amdgcn_exp2f(e[r]);
                float pe1 = __builtin_amdgcn_exp2f(e[r + 1]);
                ls2.x += pe0; ls2.y += pe1;
                pt[r]     = __float_as_uint(pe0);
                pt[r + 1] = __float_as_uint(pe1);
            }
            #pragma unroll
            for (int c2 = 0; c2 < 2; c2++) {
                int rb = c2 * 8;
                unsigned dA = PACKBF(pt[rb + 1], pt[rb + 0]);
                unsigned dB = PACKBF(pt[rb + 3], pt[rb + 2]);
                unsigned dC = PACKBF(pt[rb + 5], pt[rb + 4]);
                unsigned dD = PACKBF(pt[rb + 7], pt[rb + 6]);
                asm volatile("v_permlane32_swap_b32 %0, %1" : "+v"(dA), "+v"(dC));
                asm volatile("v_permlane32_swap_b32 %0, %1" : "+v"(dB), "+v"(dD));
                int kc = st * 2 + c2;
                pa[kc].u[0] = dA;
                pa[kc].u[1] = dB;
                pa[kc].u[2] = dC;
                pa[kc].u[3] = dD;
            }
        }
        __builtin_amdgcn_s_setprio(1);
        #pragma unroll
        for (int kc = 0; kc < 4; kc++) {
            bf16x8 vf0 = *(bf16x8*)&Vt[g][p][l31][kc * 16 + half * 8];
            bf16x8 vf1 = *(bf16x8*)&Vt[g][p][32 + l31][kc * 16 + half * 8];
            o0 = MFMA32(pa[kc].v, vf0, o0);
            o1 = MFMA32(pa[kc].v, vf1, o1);
        }
        __builtin_amdgcn_s_setprio(0);
        LBAR();
    }
    float lsum = ls2.x + ls2.y;
    float* cmb = (float*)&Ks[0][0][0][0];
    int slot = (wqw * 64 + lane) * 33;
    if (g == 1) {
        #pragma unroll
        for (int r2 = 0; r2 < 16; r2++) { cmb[slot + r2] = o0[r2]; cmb[slot + 16 + r2] = o1[r2]; }
        cmb[slot + 32] = lsum;
    }
    __syncthreads();
    if (g == 0) {
        #pragma unroll
        for (int r2 = 0; r2 < 16; r2++) { o0[r2] += cmb[slot + r2]; o1[r2] += cmb[slot + 16 + r2]; }
        lsum += cmb[slot + 32];
        float lfull = lsum + __shfl_xor(lsum, 32, 64);
        float inv = 1.001953125f / lfull;
        #pragma unroll
        for (int reg = 0; reg < 16; reg++) {
            int qrow = (reg & 3) + 8 * (reg >> 2) + 4 * half;
            float li = __shfl(inv, qrow, 64);
            int srow = q0 + wqw * 32 + qrow;
            size_t base2 = ((size_t)(b * S + srow)) * E + h * D + l31;
            ao[base2]      = f2bf(o0[reg] * li);
            ao[base2 + 32] = f2bf(o1[reg] * li);
        }
    }
}

__global__ __launch_bounds__(512) void out_proj(
    const ushort_t* __restrict__ A, const ushort_t* __restrict__ Wob,
    const float* __restrict__ bo, float* __restrict__ Y)
{
    __shared__ ushort_t As[2][128][72];
    __shared__ ushort_t Ws[2][64][72];
    int t = threadIdx.x;
    int hwb = blockIdx.x;
    int swz = (hwb & 7) * 64 + (hwb >> 3);
    int n0 = (swz & 15) * 64, m0 = (swz >> 4) * 128;
    int w = t >> 6, lane = t & 63, m = lane & 15, quad = lane >> 4;
    f32x4 acc[4];
    #pragma unroll
    for (int nt = 0; nt < 4; nt++) acc[nt] = (f32x4)0.f;
    int ar = t >> 2, ac = (t & 3) * 16;
    int wr = t >> 3, wc = (t & 7) * 8;
    const ushort_t* apb = A + (size_t)(m0 + ar) * E + ac;
    const ushort_t* wpb = Wob + (size_t)(n0 + wr) * E + wc;
    bf16x8 arg[2], wrg;
    {
        *(bf16x8*)&As[0][ar][ac]     = *(const bf16x8*)(apb);
        *(bf16x8*)&As[0][ar][ac + 8] = *(const bf16x8*)(apb + 8);
        *(bf16x8*)&Ws[0][wr][wc]     = *(const bf16x8*)(wpb);
    }
    LBAR();
    {
        arg[0] = *(const bf16x8*)(apb + 64);
        arg[1] = *(const bf16x8*)(apb + 64 + 8);
        wrg    = *(const bf16x8*)(wpb + 64);
    }
    const int KT = E / 64;
    for (int ks = 0; ks < KT; ks++) {
        int p = ks & 1;
        if (ks + 1 < KT) {
            *(bf16x8*)&As[1 - p][ar][ac]     = arg[0];
            *(bf16x8*)&As[1 - p][ar][ac + 8] = arg[1];
            *(bf16x8*)&Ws[1 - p][wr][wc]     = wrg;
        }
        if (ks + 2 < KT) {
            int off = (ks + 2) * 64;
            arg[0] = *(const bf16x8*)(apb + off);
            arg[1] = *(const bf16x8*)(apb + off + 8);
            wrg    = *(const bf16x8*)(wpb + off);
        }
        #pragma unroll
        for (int h2 = 0; h2 < 2; h2++) {
            bf16x8 af = *(bf16x8*)&As[p][w * 16 + m][h2 * 32 + quad * 8];
            #pragma unroll
            for (int nt = 0; nt < 4; nt++) {
                bf16x8 bfr = *(bf16x8*)&Ws[p][nt * 16 + m][h2 * 32 + quad * 8];
                acc[nt] = MFMA(af, bfr, acc[nt]);
            }
        }
        LBAR();
    }
    #pragma unroll
    for (int nt = 0; nt < 4; nt++)
        #pragma unroll
        for (int r = 0; r < 4; r++) {
            int row = m0 + w * 16 + quad * 4 + r;
            int col = n0 + nt * 16 + m;
            Y[(size_t)row * E + col] = acc[nt][r] + bo[col];
        }
}

extern "C" void kernel_launch(void* const* d_in, const int* in_sizes, int n_in,
                              void* d_out, int out_size, void* d_ws, size_t ws_size,
                              hipStream_t stream)
{
    const float* x  = (const float*)d_in[0];
    const float* Wq = (const float*)d_in[1];
    const float* Wk = (const float*)d_in[2];
    const float* Wv = (const float*)d_in[3];
    const float* Wo = (const float*)d_in[4];
    const float* bo = (const float*)d_in[5];
    float* Y = (float*)d_out;

    const size_t n = (size_t)B * H * S * D;    // 4M elems
    ushort_t* qw  = (ushort_t*)d_ws;           // 8 MB
    ushort_t* kw  = qw + n;                    // 8 MB
    ushort_t* vTw = kw + n;                    // 8 MB  [bh][d][s]
    ushort_t* ao  = vTw + n;                   // 8 MB  (B,S,E)
    ushort_t* wob = ao + n;                    // 2 MB

    void* kargs[] = {
        (void*)&x, (void*)&Wq, (void*)&Wk, (void*)&Wv, (void*)&Wo, (void*)&bo,
        (void*)&qw, (void*)&kw, (void*)&vTw, (void*)&ao, (void*)&wob, (void*)&Y
    };
    hipError_t err = hipLaunchCooperativeKernel((void*)fused_all, dim3(512), dim3(512),
                                                kargs, 0, stream);
    if (err != hipSuccess) {
        // Fallback: exact R17 three-launch path.
        qkv_proj<<<dim3(S / 64, B * H), 256, 0, stream>>>(x, Wq, Wk, Wv, Wo, qw, kw, vTw, wob);
        flash_attn<<<dim3((S / 128) * B * H), 512, 0, stream>>>(qw, kw, vTw, ao);
        out_proj<<<dim3(512), 512, 0, stream>>>(ao, wob, bo, Y);
    }
}

// Round 11
// 188.428 us; speedup vs baseline: 1.5372x; 1.5372x over previous
//
#include <hip/hip_runtime.h>
#include <hip/hip_bf16.h>

#define B 2
#define S 2048
#define E 1024
#define H 16
#define D 64

typedef unsigned short ushort_t;
typedef __attribute__((ext_vector_type(8))) short bf16x8;    // 8 bf16 = 4 VGPRs
typedef __attribute__((ext_vector_type(4))) float f32x4;     // 16x16 C/D frag
typedef __attribute__((ext_vector_type(16))) float f32x16;   // 32x32 C/D frag

static __device__ __forceinline__ ushort_t f2bf(float f) {
    union { float f; unsigned u; } v; v.f = f;
    unsigned r = v.u + 0x7fffu + ((v.u >> 16) & 1u);   // RNE
    return (ushort_t)(r >> 16);
}

#define MFMA(a, b, c)   __builtin_amdgcn_mfma_f32_16x16x32_bf16((a), (b), (c), 0, 0, 0)
#define MFMA32(a, b, c) __builtin_amdgcn_mfma_f32_32x32x16_bf16((a), (b), (c), 0, 0, 0)
#define PACKBF(hi, lo) __builtin_amdgcn_perm((hi), (lo), 0x07060302u)
#define WQSCALE 0.18033688011112042f   // 0.125 * log2(e)
// LDS-only barrier: waits ds ops, leaves global prefetch loads in flight.
#define LBAR() do { asm volatile("s_waitcnt lgkmcnt(0)" ::: "memory"); \
                    __builtin_amdgcn_s_barrier(); } while (0)

// softmax of one 32-row E^T sub-tile -> two packed PV A-frags (paA, paB)
#define SOFTMAX_PACK(e, paA, paB) do {                                          \
    unsigned pt[16];                                                            \
    _Pragma("unroll")                                                           \
    for (int r = 0; r < 16; r += 2) {                                           \
        float pe0 = __builtin_amdgcn_exp2f((e)[r]);                             \
        float pe1 = __builtin_amdgcn_exp2f((e)[r + 1]);                         \
        ls2.x += pe0; ls2.y += pe1;                                             \
        pt[r]     = __float_as_uint(pe0);                                       \
        pt[r + 1] = __float_as_uint(pe1);                                       \
    }                                                                           \
    {                                                                           \
        unsigned dA = PACKBF(pt[1], pt[0]), dB = PACKBF(pt[3], pt[2]);          \
        unsigned dC = PACKBF(pt[5], pt[4]), dD = PACKBF(pt[7], pt[6]);          \
        asm volatile("v_permlane32_swap_b32 %0, %1" : "+v"(dA), "+v"(dC));      \
        asm volatile("v_permlane32_swap_b32 %0, %1" : "+v"(dB), "+v"(dD));      \
        (paA).u[0] = dA; (paA).u[1] = dB; (paA).u[2] = dC; (paA).u[3] = dD;     \
    }                                                                           \
    {                                                                           \
        unsigned dA = PACKBF(pt[9],  pt[8]),  dB = PACKBF(pt[11], pt[10]);      \
        unsigned dC = PACKBF(pt[13], pt[12]), dD = PACKBF(pt[15], pt[14]);      \
        asm volatile("v_permlane32_swap_b32 %0, %1" : "+v"(dA), "+v"(dC));      \
        asm volatile("v_permlane32_swap_b32 %0, %1" : "+v"(dB), "+v"(dD));      \
        (paB).u[0] = dA; (paB).u[1] = dB; (paB).u[2] = dC; (paB).u[3] = dD;     \
    }                                                                           \
} while (0)

// ---------------- Kernel 1: QKV projection (MFMA bf16) + fused weight conversion ----------------
__global__ __launch_bounds__(256) void qkv_proj(
    const float* __restrict__ x,
    const float* __restrict__ Wq, const float* __restrict__ Wk, const float* __restrict__ Wv,
    const float* __restrict__ Wo,
    ushort_t* __restrict__ q, ushort_t* __restrict__ k, ushort_t* __restrict__ vT,
    ushort_t* __restrict__ wob)
{
    __shared__ ushort_t Xs[64][72];
    __shared__ ushort_t Wqs[64][72], Wks[64][72], Wvs[64][72];
    int t = threadIdx.x;
    int bh = blockIdx.y, b = bh >> 4, h = bh & 15;
    int s0 = blockIdx.x * 64;
    {
        int woid = blockIdx.y * 32 + blockIdx.x;
        int i = woid * 1024 + t * 4;
        float4 f = *(const float4*)(Wo + i);
        ushort4 u2; u2.x = f2bf(f.x); u2.y = f2bf(f.y); u2.z = f2bf(f.z); u2.w = f2bf(f.w);
        *(ushort4*)(wob + i) = u2;
    }
    {
        int i = t >> 2, d0 = (t & 3) * 16;
        const float* xp = x + ((size_t)(b * S + s0 + i)) * E + h * D + d0;
        #pragma unroll
        for (int c = 0; c < 16; c += 4) {
            float4 f = *(const float4*)(xp + c);
            Xs[i][d0 + c + 0] = f2bf(f.x); Xs[i][d0 + c + 1] = f2bf(f.y);
            Xs[i][d0 + c + 2] = f2bf(f.z); Xs[i][d0 + c + 3] = f2bf(f.w);
        }
    }
    {
        int e = t >> 2, d0 = (t & 3) * 16;
        const float* wqp = Wq + e * 64 + d0;
        const float* wkp = Wk + e * 64 + d0;
        const float* wvp = Wv + e * 64 + d0;
        #pragma unroll
        for (int c = 0; c < 16; c += 4) {
            float4 fq = *(const float4*)(wqp + c);
            Wqs[e][d0 + c + 0] = f2bf(fq.x * WQSCALE);
            Wqs[e][d0 + c + 1] = f2bf(fq.y * WQSCALE);
            Wqs[e][d0 + c + 2] = f2bf(fq.z * WQSCALE);
            Wqs[e][d0 + c + 3] = f2bf(fq.w * WQSCALE);
            float4 fk = *(const float4*)(wkp + c);
            Wks[e][d0 + c + 0] = f2bf(fk.x); Wks[e][d0 + c + 1] = f2bf(fk.y);
            Wks[e][d0 + c + 2] = f2bf(fk.z); Wks[e][d0 + c + 3] = f2bf(fk.w);
            float4 fv = *(const float4*)(wvp + c);
            Wvs[e][d0 + c + 0] = f2bf(fv.x); Wvs[e][d0 + c + 1] = f2bf(fv.y);
            Wvs[e][d0 + c + 2] = f2bf(fv.z); Wvs[e][d0 + c + 3] = f2bf(fv.w);
        }
    }
    __syncthreads();
    int w = t >> 6, lane = t & 63, m = lane & 15, quad = lane >> 4;
    bf16x8 a0 = *(bf16x8*)&Xs[16 * w + m][quad * 8];
    bf16x8 a1 = *(bf16x8*)&Xs[16 * w + m][32 + quad * 8];
    f32x4 cq[4], ck[4], cv[4];
    #pragma unroll
    for (int nt = 0; nt < 4; nt++) { cq[nt] = (f32x4)0.f; ck[nt] = (f32x4)0.f; cv[nt] = (f32x4)0.f; }
    #pragma unroll
    for (int nt = 0; nt < 4; nt++) {
        bf16x8 b0, b1;
        b0 = *(bf16x8*)&Wqs[nt * 16 + m][quad * 8]; b1 = *(bf16x8*)&Wqs[nt * 16 + m][32 + quad * 8];
        cq[nt] = MFMA(a0, b0, cq[nt]); cq[nt] = MFMA(a1, b1, cq[nt]);
        b0 = *(bf16x8*)&Wks[nt * 16 + m][quad * 8]; b1 = *(bf16x8*)&Wks[nt * 16 + m][32 + quad * 8];
        ck[nt] = MFMA(a0, b0, ck[nt]); ck[nt] = MFMA(a1, b1, ck[nt]);
        b0 = *(bf16x8*)&Wvs[nt * 16 + m][quad * 8]; b1 = *(bf16x8*)&Wvs[nt * 16 + m][32 + quad * 8];
        cv[nt] = MFMA(a0, b0, cv[nt]); cv[nt] = MFMA(a1, b1, cv[nt]);
    }
    size_t base = (size_t)bh * S + s0;
    #pragma unroll
    for (int nt = 0; nt < 4; nt++)
        #pragma unroll
        for (int r = 0; r < 4; r++) {
            size_t idx = (base + 16 * w + quad * 4 + r) * D + nt * 16 + m;
            q[idx] = f2bf(cq[nt][r]);
            k[idx] = f2bf(ck[nt][r]);
        }
    __syncthreads();
    #pragma unroll
    for (int nt = 0; nt < 4; nt++)
        #pragma unroll
        for (int r = 0; r < 4; r++)
            Wvs[nt * 16 + m][16 * w + quad * 4 + r] = f2bf(cv[nt][r]);
    __syncthreads();
    {
        int d0 = t >> 2, sc = (t & 3) * 16;
        ushort_t* vp = vT + ((size_t)bh * D + d0) * S + s0 + sc;
        *(bf16x8*)(vp)     = *(bf16x8*)&Wvs[d0][sc];
        *(bf16x8*)(vp + 8) = *(bf16x8*)&Wvs[d0][sc + 8];
    }
}

// ---------------- Kernel 2: flash attention (R17 + hoisted V fragments) ----------------
// R19: fusion reverted (grid.sync + cross-XCD dirty-line reads = 2x regression).
// One change vs R17: the 8 PV V-frag ds_reads are hoisted into named registers
// between QK(st0) and softmax(st0) -- the ~150cy exp2/pack chain covers their
// latency, and PV MFMAs issue with operands resident. R17's VGPR=64 showed the
// compiler parked at the 64-cliff and refused this hoist; LDS caps occupancy at
// 2 blocks/CU so VGPR 64->~96 is free under __launch_bounds__(512,4).
__global__ __launch_bounds__(512, 4) void flash_attn(
    const ushort_t* __restrict__ q, const ushort_t* __restrict__ k,
    const ushort_t* __restrict__ vT, ushort_t* __restrict__ ao)
{
    __shared__ ushort_t Ks[2][2][64][72];   // [grp][buf][s_local][d]
    __shared__ ushort_t Vt[2][2][64][72];   // [grp][buf][d][s_local]
    int t = threadIdx.x;
    int lin = blockIdx.x;                   // 512 blocks, 1-D
    int xcd = lin & 7, loc = lin >> 3;      // XCD round-robin %8
    int bh = xcd * 4 + (loc >> 4);          // 4 bh per XCD (2 MB K/V <= 4 MB L2)
    int q0 = (loc & 15) * 128;              // 16 q-tiles per bh
    int b = bh >> 4, h = bh & 15;
    int w = t >> 6, lane = t & 63, l31 = lane & 31, half = lane >> 5;
    int g = w >> 2, wq = w & 3;             // kv-split group, q-row wave
    int tg = t & 255;                       // staging id within group

    const ushort_t* qb = q + ((size_t)bh * S + q0) * D;
    const ushort_t* kb = k + (size_t)bh * S * D;
    const ushort_t* vb = vT + (size_t)bh * D * S;

    bf16x8 qf[4];
    {
        const ushort_t* qp = qb + (size_t)(wq * 32 + l31) * D + half * 8;
        #pragma unroll
        for (int c = 0; c < 4; c++) qf[c] = *(const bf16x8*)(qp + c * 16);
    }

    f32x16 o0 = (f32x16)0.f, o1 = (f32x16)0.f;
    float2 ls2 = make_float2(0.f, 0.f);

    int sr = tg >> 2, scc = (tg & 3) * 16;
    bf16x8 kp0, kp1, vp0, vp1;

    {
        int k00 = g * 64;
        const ushort_t* kp = kb + (size_t)(k00 + sr) * D + scc;
        const ushort_t* vp = vb + (size_t)sr * S + k00 + scc;
        kp0 = *(const bf16x8*)(kp);     kp1 = *(const bf16x8*)(kp + 8);
        vp0 = *(const bf16x8*)(vp);     vp1 = *(const bf16x8*)(vp + 8);
        *(bf16x8*)&Ks[g][0][sr][scc]     = kp0;
        *(bf16x8*)&Ks[g][0][sr][scc + 8] = kp1;
        *(bf16x8*)&Vt[g][0][sr][scc]     = vp0;
        *(bf16x8*)&Vt[g][0][sr][scc + 8] = vp1;
    }
    LBAR();
    {
        int k01 = (2 + g) * 64;
        const ushort_t* kp = kb + (size_t)(k01 + sr) * D + scc;
        const ushort_t* vp = vb + (size_t)sr * S + k01 + scc;
        kp0 = *(const bf16x8*)(kp);     kp1 = *(const bf16x8*)(kp + 8);
        vp0 = *(const bf16x8*)(vp);     vp1 = *(const bf16x8*)(vp + 8);
    }

    const int NJ = S / 128;   // 16 tiles per group (global tile = 2*jt + g)
    for (int jt = 0; jt < NJ; jt++) {
        int p = jt & 1;
        if (jt + 1 < NJ) {
            *(bf16x8*)&Ks[g][1 - p][sr][scc]     = kp0;
            *(bf16x8*)&Ks[g][1 - p][sr][scc + 8] = kp1;
            *(bf16x8*)&Vt[g][1 - p][sr][scc]     = vp0;
            *(bf16x8*)&Vt[g][1 - p][sr][scc + 8] = vp1;
        }
        if (jt + 2 < NJ) {
            int k0n = (2 * (jt + 2) + g) * 64;
            const ushort_t* kp = kb + (size_t)(k0n + sr) * D + scc;
            const ushort_t* vp = vb + (size_t)sr * S + k0n + scc;
            kp0 = *(const bf16x8*)(kp);     kp1 = *(const bf16x8*)(kp + 8);
            vp0 = *(const bf16x8*)(vp);     vp1 = *(const bf16x8*)(vp + 8);
        }

        union pu { unsigned u[4]; bf16x8 v; } pa[4];

        // ---- QK^T sub-tile 0 ----
        f32x16 e0 = (f32x16)0.f;
        __builtin_amdgcn_s_setprio(1);
        #pragma unroll
        for (int c = 0; c < 4; c++) {
            bf16x8 ka = *(bf16x8*)&Ks[g][p][l31][c * 16 + half * 8];
            e0 = MFMA32(ka, qf[c], e0);
        }
        __builtin_amdgcn_s_setprio(0);

        // ---- hoist all 8 V frags for this tile (latency covered by softmax) ----
        bf16x8 vflo[4], vfhi[4];
        #pragma unroll
        for (int kc = 0; kc < 4; kc++) {
            vflo[kc] = *(bf16x8*)&Vt[g][p][l31][kc * 16 + half * 8];
            vfhi[kc] = *(bf16x8*)&Vt[g][p][32 + l31][kc * 16 + half * 8];
        }

        SOFTMAX_PACK(e0, pa[0], pa[1]);

        // ---- QK^T sub-tile 1 ----
        f32x16 e1 = (f32x16)0.f;
        __builtin_amdgcn_s_setprio(1);
        #pragma unroll
        for (int c = 0; c < 4; c++) {
            bf16x8 ka = *(bf16x8*)&Ks[g][p][32 + l31][c * 16 + half * 8];
            e1 = MFMA32(ka, qf[c], e1);
        }
        __builtin_amdgcn_s_setprio(0);

        SOFTMAX_PACK(e1, pa[2], pa[3]);

        // ---- O += P V : operands already in registers ----
        __builtin_amdgcn_s_setprio(1);
        #pragma unroll
        for (int kc = 0; kc < 4; kc++) {
            o0 = MFMA32(pa[kc].v, vflo[kc], o0);
            o1 = MFMA32(pa[kc].v, vfhi[kc], o1);
        }
        __builtin_amdgcn_s_setprio(0);
        LBAR();   // LDS-only: prefetch loads NOT drained here
    }

    // ---- split-kv combine (group1 -> LDS -> group0 adds), then epilogue ----
    float lsum = ls2.x + ls2.y;
    float* cmb = (float*)&Ks[0][0][0][0];
    int slot = (wq * 64 + lane) * 33;
    if (g == 1) {
        #pragma unroll
        for (int r2 = 0; r2 < 16; r2++) { cmb[slot + r2] = o0[r2]; cmb[slot + 16 + r2] = o1[r2]; }
        cmb[slot + 32] = lsum;
    }
    __syncthreads();
    if (g == 0) {
        #pragma unroll
        for (int r2 = 0; r2 < 16; r2++) { o0[r2] += cmb[slot + r2]; o1[r2] += cmb[slot + 16 + r2]; }
        lsum += cmb[slot + 32];
        float lfull = lsum + __shfl_xor(lsum, 32, 64);
        float inv = 1.001953125f / lfull;
        #pragma unroll
        for (int reg = 0; reg < 16; reg++) {
            int qrow = (reg & 3) + 8 * (reg >> 2) + 4 * half;
            float li = __shfl(inv, qrow, 64);
            int srow = q0 + wq * 32 + qrow;
            size_t base2 = ((size_t)(b * S + srow)) * E + h * D + l31;
            ao[base2]      = f2bf(o0[reg] * li);
            ao[base2 + 32] = f2bf(o1[reg] * li);
        }
    }
}

// ---------------- Kernel 3: output projection (128m x 64n, 8 waves, LDS-only barriers) ----------------
__global__ __launch_bounds__(512) void out_proj(
    const ushort_t* __restrict__ A, const ushort_t* __restrict__ Wob,
    const float* __restrict__ bo, float* __restrict__ Y)
{
    __shared__ ushort_t As[2][128][72];
    __shared__ ushort_t Ws[2][64][72];
    int t = threadIdx.x;
    int hwb = blockIdx.x;
    int swz = (hwb & 7) * 64 + (hwb >> 3);
    int n0 = (swz & 15) * 64, m0 = (swz >> 4) * 128;
    int w = t >> 6, lane = t & 63, m = lane & 15, quad = lane >> 4;
    f32x4 acc[4];
    #pragma unroll
    for (int nt = 0; nt < 4; nt++) acc[nt] = (f32x4)0.f;
    int ar = t >> 2, ac = (t & 3) * 16;
    int wr = t >> 3, wc = (t & 7) * 8;
    const ushort_t* apb = A + (size_t)(m0 + ar) * E + ac;
    const ushort_t* wpb = Wob + (size_t)(n0 + wr) * E + wc;
    bf16x8 arg[2], wrg;
    {
        *(bf16x8*)&As[0][ar][ac]     = *(const bf16x8*)(apb);
        *(bf16x8*)&As[0][ar][ac + 8] = *(const bf16x8*)(apb + 8);
        *(bf16x8*)&Ws[0][wr][wc]     = *(const bf16x8*)(wpb);
    }
    LBAR();
    {
        arg[0] = *(const bf16x8*)(apb + 64);
        arg[1] = *(const bf16x8*)(apb + 64 + 8);
        wrg    = *(const bf16x8*)(wpb + 64);
    }
    const int KT = E / 64;
    for (int ks = 0; ks < KT; ks++) {
        int p = ks & 1;
        if (ks + 1 < KT) {
            *(bf16x8*)&As[1 - p][ar][ac]     = arg[0];
            *(bf16x8*)&As[1 - p][ar][ac + 8] = arg[1];
            *(bf16x8*)&Ws[1 - p][wr][wc]     = wrg;
        }
        if (ks + 2 < KT) {
            int off = (ks + 2) * 64;
            arg[0] = *(const bf16x8*)(apb + off);
            arg[1] = *(const bf16x8*)(apb + off + 8);
            wrg    = *(const bf16x8*)(wpb + off);
        }
        #pragma unroll
        for (int h2 = 0; h2 < 2; h2++) {
            bf16x8 af = *(bf16x8*)&As[p][w * 16 + m][h2 * 32 + quad * 8];
            #pragma unroll
            for (int nt = 0; nt < 4; nt++) {
                bf16x8 bfr = *(bf16x8*)&Ws[p][nt * 16 + m][h2 * 32 + quad * 8];
                acc[nt] = MFMA(af, bfr, acc[nt]);
            }
        }
        LBAR();
    }
    #pragma unroll
    for (int nt = 0; nt < 4; nt++)
        #pragma unroll
        for (int r = 0; r < 4; r++) {
            int row = m0 + w * 16 + quad * 4 + r;
            int col = n0 + nt * 16 + m;
            Y[(size_t)row * E + col] = acc[nt][r] + bo[col];
        }
}

extern "C" void kernel_launch(void* const* d_in, const int* in_sizes, int n_in,
                              void* d_out, int out_size, void* d_ws, size_t ws_size,
                              hipStream_t stream)
{
    const float* x  = (const float*)d_in[0];
    const float* Wq = (const float*)d_in[1];
    const float* Wk = (const float*)d_in[2];
    const float* Wv = (const float*)d_in[3];
    const float* Wo = (const float*)d_in[4];
    const float* bo = (const float*)d_in[5];
    float* Y = (float*)d_out;

    const size_t n = (size_t)B * H * S * D;    // 4M elems
    ushort_t* qw  = (ushort_t*)d_ws;           // 8 MB
    ushort_t* kw  = qw + n;                    // 8 MB
    ushort_t* vTw = kw + n;                    // 8 MB  [bh][d][s]
    ushort_t* ao  = vTw + n;                   // 8 MB  (B,S,E)
    ushort_t* wob = ao + n;                    // 2 MB

    qkv_proj<<<dim3(S / 64, B * H), 256, 0, stream>>>(x, Wq, Wk, Wv, Wo, qw, kw, vTw, wob);
    flash_attn<<<dim3((S / 128) * B * H), 512, 0, stream>>>(qw, kw, vTw, ao);
    out_proj<<<dim3(512), 512, 0, stream>>>(ao, wob, bo, Y);
}

// Round 12
// 144.749 us; speedup vs baseline: 2.0011x; 1.3018x over previous
//
#include <hip/hip_runtime.h>
#include <hip/hip_bf16.h>

#define B 2
#define S 2048
#define E 1024
#define H 16
#define D 64

typedef unsigned short ushort_t;
typedef __attribute__((ext_vector_type(8))) short bf16x8;    // 8 bf16 = 4 VGPRs
typedef __attribute__((ext_vector_type(4))) float f32x4;     // 16x16 C/D frag
typedef __attribute__((ext_vector_type(16))) float f32x16;   // 32x32 C/D frag

static __device__ __forceinline__ ushort_t f2bf(float f) {
    union { float f; unsigned u; } v; v.f = f;
    unsigned r = v.u + 0x7fffu + ((v.u >> 16) & 1u);   // RNE
    return (ushort_t)(r >> 16);
}

#define MFMA(a, b, c)   __builtin_amdgcn_mfma_f32_16x16x32_bf16((a), (b), (c), 0, 0, 0)
#define MFMA32(a, b, c) __builtin_amdgcn_mfma_f32_32x32x16_bf16((a), (b), (c), 0, 0, 0)
#define PACKBF(hi, lo) __builtin_amdgcn_perm((hi), (lo), 0x07060302u)
#define WQSCALE 0.18033688011112042f   // 0.125 * log2(e)
// LDS-only barrier: waits ds ops, leaves global prefetch loads in flight.
#define LBAR() do { asm volatile("s_waitcnt lgkmcnt(0)" ::: "memory"); \
                    __builtin_amdgcn_s_barrier(); } while (0)

// ---------------- Kernel 1: QKV projection (MFMA bf16) + fused weight conversion ----------------
__global__ __launch_bounds__(256) void qkv_proj(
    const float* __restrict__ x,
    const float* __restrict__ Wq, const float* __restrict__ Wk, const float* __restrict__ Wv,
    const float* __restrict__ Wo,
    ushort_t* __restrict__ q, ushort_t* __restrict__ k, ushort_t* __restrict__ vT,
    ushort_t* __restrict__ wob)
{
    __shared__ ushort_t Xs[64][72];
    __shared__ ushort_t Wqs[64][72], Wks[64][72], Wvs[64][72];
    int t = threadIdx.x;
    int bh = blockIdx.y, b = bh >> 4, h = bh & 15;
    int s0 = blockIdx.x * 64;
    {
        int woid = blockIdx.y * 32 + blockIdx.x;
        int i = woid * 1024 + t * 4;
        float4 f = *(const float4*)(Wo + i);
        ushort4 u2; u2.x = f2bf(f.x); u2.y = f2bf(f.y); u2.z = f2bf(f.z); u2.w = f2bf(f.w);
        *(ushort4*)(wob + i) = u2;
    }
    {
        int i = t >> 2, d0 = (t & 3) * 16;
        const float* xp = x + ((size_t)(b * S + s0 + i)) * E + h * D + d0;
        #pragma unroll
        for (int c = 0; c < 16; c += 4) {
            float4 f = *(const float4*)(xp + c);
            Xs[i][d0 + c + 0] = f2bf(f.x); Xs[i][d0 + c + 1] = f2bf(f.y);
            Xs[i][d0 + c + 2] = f2bf(f.z); Xs[i][d0 + c + 3] = f2bf(f.w);
        }
    }
    {
        int e = t >> 2, d0 = (t & 3) * 16;
        const float* wqp = Wq + e * 64 + d0;
        const float* wkp = Wk + e * 64 + d0;
        const float* wvp = Wv + e * 64 + d0;
        #pragma unroll
        for (int c = 0; c < 16; c += 4) {
            float4 fq = *(const float4*)(wqp + c);
            Wqs[e][d0 + c + 0] = f2bf(fq.x * WQSCALE);
            Wqs[e][d0 + c + 1] = f2bf(fq.y * WQSCALE);
            Wqs[e][d0 + c + 2] = f2bf(fq.z * WQSCALE);
            Wqs[e][d0 + c + 3] = f2bf(fq.w * WQSCALE);
            float4 fk = *(const float4*)(wkp + c);
            Wks[e][d0 + c + 0] = f2bf(fk.x); Wks[e][d0 + c + 1] = f2bf(fk.y);
            Wks[e][d0 + c + 2] = f2bf(fk.z); Wks[e][d0 + c + 3] = f2bf(fk.w);
            float4 fv = *(const float4*)(wvp + c);
            Wvs[e][d0 + c + 0] = f2bf(fv.x); Wvs[e][d0 + c + 1] = f2bf(fv.y);
            Wvs[e][d0 + c + 2] = f2bf(fv.z); Wvs[e][d0 + c + 3] = f2bf(fv.w);
        }
    }
    __syncthreads();
    int w = t >> 6, lane = t & 63, m = lane & 15, quad = lane >> 4;
    bf16x8 a0 = *(bf16x8*)&Xs[16 * w + m][quad * 8];
    bf16x8 a1 = *(bf16x8*)&Xs[16 * w + m][32 + quad * 8];
    f32x4 cq[4], ck[4], cv[4];
    #pragma unroll
    for (int nt = 0; nt < 4; nt++) { cq[nt] = (f32x4)0.f; ck[nt] = (f32x4)0.f; cv[nt] = (f32x4)0.f; }
    #pragma unroll
    for (int nt = 0; nt < 4; nt++) {
        bf16x8 b0, b1;
        b0 = *(bf16x8*)&Wqs[nt * 16 + m][quad * 8]; b1 = *(bf16x8*)&Wqs[nt * 16 + m][32 + quad * 8];
        cq[nt] = MFMA(a0, b0, cq[nt]); cq[nt] = MFMA(a1, b1, cq[nt]);
        b0 = *(bf16x8*)&Wks[nt * 16 + m][quad * 8]; b1 = *(bf16x8*)&Wks[nt * 16 + m][32 + quad * 8];
        ck[nt] = MFMA(a0, b0, ck[nt]); ck[nt] = MFMA(a1, b1, ck[nt]);
        b0 = *(bf16x8*)&Wvs[nt * 16 + m][quad * 8]; b1 = *(bf16x8*)&Wvs[nt * 16 + m][32 + quad * 8];
        cv[nt] = MFMA(a0, b0, cv[nt]); cv[nt] = MFMA(a1, b1, cv[nt]);
    }
    size_t base = (size_t)bh * S + s0;
    #pragma unroll
    for (int nt = 0; nt < 4; nt++)
        #pragma unroll
        for (int r = 0; r < 4; r++) {
            size_t idx = (base + 16 * w + quad * 4 + r) * D + nt * 16 + m;
            q[idx] = f2bf(cq[nt][r]);
            k[idx] = f2bf(ck[nt][r]);
        }
    __syncthreads();
    #pragma unroll
    for (int nt = 0; nt < 4; nt++)
        #pragma unroll
        for (int r = 0; r < 4; r++)
            Wvs[nt * 16 + m][16 * w + quad * 4 + r] = f2bf(cv[nt][r]);
    __syncthreads();
    {
        int d0 = t >> 2, sc = (t & 3) * 16;
        ushort_t* vp = vT + ((size_t)bh * D + d0) * S + s0 + sc;
        *(bf16x8*)(vp)     = *(bf16x8*)&Wvs[d0][sc];
        *(bf16x8*)(vp + 8) = *(bf16x8*)&Wvs[d0][sc + 8];
    }
}

// ---------------- Kernel 2: flash attention (exact R17: best measured 44.9 us) ----------------
// R19 lesson: allocator pins this kernel at 64 VGPR; any extra live state spills
// to scratch (170 MB traffic, 2x regression). Do not hoist; do not restructure.
__global__ __launch_bounds__(512, 4) void flash_attn(
    const ushort_t* __restrict__ q, const ushort_t* __restrict__ k,
    const ushort_t* __restrict__ vT, ushort_t* __restrict__ ao)
{
    __shared__ ushort_t Ks[2][2][64][72];   // [grp][buf][s_local][d]
    __shared__ ushort_t Vt[2][2][64][72];   // [grp][buf][d][s_local]
    int t = threadIdx.x;
    int lin = blockIdx.x;                   // 512 blocks, 1-D
    int xcd = lin & 7, loc = lin >> 3;      // XCD round-robin %8
    int bh = xcd * 4 + (loc >> 4);          // 4 bh per XCD (2 MB K/V <= 4 MB L2)
    int q0 = (loc & 15) * 128;              // 16 q-tiles per bh
    int b = bh >> 4, h = bh & 15;
    int w = t >> 6, lane = t & 63, l31 = lane & 31, half = lane >> 5;
    int g = w >> 2, wq = w & 3;             // kv-split group, q-row wave
    int tg = t & 255;                       // staging id within group

    const ushort_t* qb = q + ((size_t)bh * S + q0) * D;
    const ushort_t* kb = k + (size_t)bh * S * D;
    const ushort_t* vb = vT + (size_t)bh * D * S;

    bf16x8 qf[4];
    {
        const ushort_t* qp = qb + (size_t)(wq * 32 + l31) * D + half * 8;
        #pragma unroll
        for (int c = 0; c < 4; c++) qf[c] = *(const bf16x8*)(qp + c * 16);
    }

    f32x16 o0 = (f32x16)0.f, o1 = (f32x16)0.f;
    float2 ls2 = make_float2(0.f, 0.f);

    int sr = tg >> 2, scc = (tg & 3) * 16;
    bf16x8 kp0, kp1, vp0, vp1;

    {
        int k00 = g * 64;
        const ushort_t* kp = kb + (size_t)(k00 + sr) * D + scc;
        const ushort_t* vp = vb + (size_t)sr * S + k00 + scc;
        kp0 = *(const bf16x8*)(kp);     kp1 = *(const bf16x8*)(kp + 8);
        vp0 = *(const bf16x8*)(vp);     vp1 = *(const bf16x8*)(vp + 8);
        *(bf16x8*)&Ks[g][0][sr][scc]     = kp0;
        *(bf16x8*)&Ks[g][0][sr][scc + 8] = kp1;
        *(bf16x8*)&Vt[g][0][sr][scc]     = vp0;
        *(bf16x8*)&Vt[g][0][sr][scc + 8] = vp1;
    }
    LBAR();
    {
        int k01 = (2 + g) * 64;
        const ushort_t* kp = kb + (size_t)(k01 + sr) * D + scc;
        const ushort_t* vp = vb + (size_t)sr * S + k01 + scc;
        kp0 = *(const bf16x8*)(kp);     kp1 = *(const bf16x8*)(kp + 8);
        vp0 = *(const bf16x8*)(vp);     vp1 = *(const bf16x8*)(vp + 8);
    }

    const int NJ = S / 128;   // 16 tiles per group (global tile = 2*jt + g)
    for (int jt = 0; jt < NJ; jt++) {
        int p = jt & 1;
        if (jt + 1 < NJ) {
            *(bf16x8*)&Ks[g][1 - p][sr][scc]     = kp0;
            *(bf16x8*)&Ks[g][1 - p][sr][scc + 8] = kp1;
            *(bf16x8*)&Vt[g][1 - p][sr][scc]     = vp0;
            *(bf16x8*)&Vt[g][1 - p][sr][scc + 8] = vp1;
        }
        if (jt + 2 < NJ) {
            int k0n = (2 * (jt + 2) + g) * 64;
            const ushort_t* kp = kb + (size_t)(k0n + sr) * D + scc;
            const ushort_t* vp = vb + (size_t)sr * S + k0n + scc;
            kp0 = *(const bf16x8*)(kp);     kp1 = *(const bf16x8*)(kp + 8);
            vp0 = *(const bf16x8*)(vp);     vp1 = *(const bf16x8*)(vp + 8);
        }

        union { unsigned u[4]; bf16x8 v; } pa[4];
        #pragma unroll
        for (int st = 0; st < 2; st++) {
            f32x16 e = (f32x16)0.f;
            __builtin_amdgcn_s_setprio(1);
            #pragma unroll
            for (int c = 0; c < 4; c++) {
                bf16x8 ka = *(bf16x8*)&Ks[g][p][st * 32 + l31][c * 16 + half * 8];
                e = MFMA32(ka, qf[c], e);
            }
            __builtin_amdgcn_s_setprio(0);
            unsigned pt[16];
            #pragma unroll
            for (int r = 0; r < 16; r += 2) {
                float pe0 = __builtin_amdgcn_exp2f(e[r]);
                float pe1 = __builtin_amdgcn_exp2f(e[r + 1]);
                ls2.x += pe0; ls2.y += pe1;
                pt[r]     = __float_as_uint(pe0);
                pt[r + 1] = __float_as_uint(pe1);
            }
            #pragma unroll
            for (int c2 = 0; c2 < 2; c2++) {
                int rb = c2 * 8;
                unsigned dA = PACKBF(pt[rb + 1], pt[rb + 0]);
                unsigned dB = PACKBF(pt[rb + 3], pt[rb + 2]);
                unsigned dC = PACKBF(pt[rb + 5], pt[rb + 4]);
                unsigned dD = PACKBF(pt[rb + 7], pt[rb + 6]);
                asm volatile("v_permlane32_swap_b32 %0, %1" : "+v"(dA), "+v"(dC));
                asm volatile("v_permlane32_swap_b32 %0, %1" : "+v"(dB), "+v"(dD));
                int kc = st * 2 + c2;
                pa[kc].u[0] = dA;
                pa[kc].u[1] = dB;
                pa[kc].u[2] = dC;
                pa[kc].u[3] = dD;
            }
        }

        __builtin_amdgcn_s_setprio(1);
        #pragma unroll
        for (int kc = 0; kc < 4; kc++) {
            bf16x8 vf0 = *(bf16x8*)&Vt[g][p][l31][kc * 16 + half * 8];
            bf16x8 vf1 = *(bf16x8*)&Vt[g][p][32 + l31][kc * 16 + half * 8];
            o0 = MFMA32(pa[kc].v, vf0, o0);
            o1 = MFMA32(pa[kc].v, vf1, o1);
        }
        __builtin_amdgcn_s_setprio(0);
        LBAR();   // LDS-only: prefetch loads NOT drained here
    }

    float lsum = ls2.x + ls2.y;
    float* cmb = (float*)&Ks[0][0][0][0];
    int slot = (wq * 64 + lane) * 33;
    if (g == 1) {
        #pragma unroll
        for (int r2 = 0; r2 < 16; r2++) { cmb[slot + r2] = o0[r2]; cmb[slot + 16 + r2] = o1[r2]; }
        cmb[slot + 32] = lsum;
    }
    __syncthreads();
    if (g == 0) {
        #pragma unroll
        for (int r2 = 0; r2 < 16; r2++) { o0[r2] += cmb[slot + r2]; o1[r2] += cmb[slot + 16 + r2]; }
        lsum += cmb[slot + 32];
        float lfull = lsum + __shfl_xor(lsum, 32, 64);
        float inv = 1.001953125f / lfull;
        #pragma unroll
        for (int reg = 0; reg < 16; reg++) {
            int qrow = (reg & 3) + 8 * (reg >> 2) + 4 * half;
            float li = __shfl(inv, qrow, 64);
            int srow = q0 + wq * 32 + qrow;
            size_t base2 = ((size_t)(b * S + srow)) * E + h * D + l31;
            ao[base2]      = f2bf(o0[reg] * li);
            ao[base2 + 32] = f2bf(o1[reg] * li);
        }
    }
}

// ---------------- Kernel 3: output projection (A-direct, Ws-only LDS) ----------------
// R20: wave w reads ONLY A-rows w*16..w*16+15 -> the A LDS tile had zero
// cross-wave reuse. Drop it: each thread double-buffers its own two A-frags in
// registers straight from global (L2/L3-resident), explicit prefetch with one
// full iteration of latency cover (R6 lesson). LDS 55.3 -> 18.4 KB (Ws only)
// -> wave-cap occupancy 16 -> 32 waves/CU (the R1 mechanism). ~50 VGPR state,
// safely under the 64 cliff. MFMA order per-acc unchanged (h2=0 then h2=1).
__global__ __launch_bounds__(512, 4) void out_proj(
    const ushort_t* __restrict__ A, const ushort_t* __restrict__ Wob,
    const float* __restrict__ bo, float* __restrict__ Y)
{
    __shared__ ushort_t Ws[2][64][72];   // 18,432 B
    int t = threadIdx.x;
    int hwb = blockIdx.x;                          // 512 blocks, 1-D
    int swz = (hwb & 7) * 64 + (hwb >> 3);         // XCD-chunked, bijective
    int n0 = (swz & 15) * 64, m0 = (swz >> 4) * 128;
    int w = t >> 6, lane = t & 63, m = lane & 15, quad = lane >> 4;
    f32x4 acc[4];
    #pragma unroll
    for (int nt = 0; nt < 4; nt++) acc[nt] = (f32x4)0.f;

    int wr = t >> 3, wc = (t & 7) * 8;             // W: 64 rows x 8x8
    const ushort_t* wpb = Wob + (size_t)(n0 + wr) * E + wc;
    // per-lane A row pointer: wave w owns rows w*16 + m
    const ushort_t* apA = A + (size_t)(m0 + w * 16 + m) * E + quad * 8;

    bf16x8 wrg, afc0, afc1, afn0, afn1;
    {   // k-step 0: W -> LDS buf 0; A -> current regs
        *(bf16x8*)&Ws[0][wr][wc] = *(const bf16x8*)(wpb);
        afc0 = *(const bf16x8*)(apA);        // ks=0, h2=0
        afc1 = *(const bf16x8*)(apA + 32);   // ks=0, h2=1
    }
    LBAR();
    {   // k-step 1 prefetch -> regs
        wrg  = *(const bf16x8*)(wpb + 64);
        afn0 = *(const bf16x8*)(apA + 64);
        afn1 = *(const bf16x8*)(apA + 96);
    }

    const int KT = E / 64;   // 16
    for (int ks = 0; ks < KT; ks++) {
        int p = ks & 1;
        if (ks + 1 < KT)     // write W k-step ks+1 (reg) into other buffer
            *(bf16x8*)&Ws[1 - p][wr][wc] = wrg;
        if (ks + 2 < KT)     // issue W load for ks+2 (stays in flight across LBAR)
            wrg = *(const bf16x8*)(wpb + (ks + 2) * 64);

        bf16x8 a0 = afc0, a1 = afc1;
        #pragma unroll
        for (int nt = 0; nt < 4; nt++) {
            bf16x8 b0 = *(bf16x8*)&Ws[p][nt * 16 + m][quad * 8];
            bf16x8 b1 = *(bf16x8*)&Ws[p][nt * 16 + m][32 + quad * 8];
            acc[nt] = MFMA(a0, b0, acc[nt]);
            acc[nt] = MFMA(a1, b1, acc[nt]);
        }

        // rotate A double-buffer; issue loads for ks+2
        afc0 = afn0; afc1 = afn1;
        if (ks + 2 < KT) {
            int off = (ks + 2) * 64;
            afn0 = *(const bf16x8*)(apA + off);
            afn1 = *(const bf16x8*)(apA + off + 32);
        }
        LBAR();
    }
    #pragma unroll
    for (int nt = 0; nt < 4; nt++)
        #pragma unroll
        for (int r = 0; r < 4; r++) {
            int row = m0 + w * 16 + quad * 4 + r;
            int col = n0 + nt * 16 + m;
            Y[(size_t)row * E + col] = acc[nt][r] + bo[col];
        }
}

extern "C" void kernel_launch(void* const* d_in, const int* in_sizes, int n_in,
                              void* d_out, int out_size, void* d_ws, size_t ws_size,
                              hipStream_t stream)
{
    const float* x  = (const float*)d_in[0];
    const float* Wq = (const float*)d_in[1];
    const float* Wk = (const float*)d_in[2];
    const float* Wv = (const float*)d_in[3];
    const float* Wo = (const float*)d_in[4];
    const float* bo = (const float*)d_in[5];
    float* Y = (float*)d_out;

    const size_t n = (size_t)B * H * S * D;    // 4M elems
    ushort_t* qw  = (ushort_t*)d_ws;           // 8 MB
    ushort_t* kw  = qw + n;                    // 8 MB
    ushort_t* vTw = kw + n;                    // 8 MB  [bh][d][s]
    ushort_t* ao  = vTw + n;                   // 8 MB  (B,S,E)
    ushort_t* wob = ao + n;                    // 2 MB

    qkv_proj<<<dim3(S / 64, B * H), 256, 0, stream>>>(x, Wq, Wk, Wv, Wo, qw, kw, vTw, wob);
    flash_attn<<<dim3((S / 128) * B * H), 512, 0, stream>>>(qw, kw, vTw, ao);
    out_proj<<<dim3(512), 512, 0, stream>>>(ao, wob, bo, Y);
}

// Round 14
// 141.694 us; speedup vs baseline: 2.0443x; 1.0216x over previous
//
#include <hip/hip_runtime.h>
#include <hip/hip_bf16.h>

#define B 2
#define S 2048
#define E 1024
#define H 16
#define D 64

typedef unsigned short ushort_t;
typedef __attribute__((ext_vector_type(8))) short bf16x8;    // 8 bf16 = 4 VGPRs
typedef __attribute__((ext_vector_type(4))) float f32x4;     // 16x16 C/D frag
typedef __attribute__((ext_vector_type(16))) float f32x16;   // 32x32 C/D frag

static __device__ __forceinline__ ushort_t f2bf(float f) {
    union { float f; unsigned u; } v; v.f = f;
    unsigned r = v.u + 0x7fffu + ((v.u >> 16) & 1u);   // RNE
    return (ushort_t)(r >> 16);
}
// pack two floats into one dword of RNE-rounded bf16 pair: [hi16(f1):hi16(f0)]
static __device__ __forceinline__ unsigned pack2bf(float f0, float f1) {
    unsigned u0 = __float_as_uint(f0), u1 = __float_as_uint(f1);
    u0 += 0x7fffu + ((u0 >> 16) & 1u);
    u1 += 0x7fffu + ((u1 >> 16) & 1u);
    return __builtin_amdgcn_perm(u1, u0, 0x07060302u);
}

#define MFMA(a, b, c)   __builtin_amdgcn_mfma_f32_16x16x32_bf16((a), (b), (c), 0, 0, 0)
#define MFMA32(a, b, c) __builtin_amdgcn_mfma_f32_32x32x16_bf16((a), (b), (c), 0, 0, 0)
#define PACKBF(hi, lo) __builtin_amdgcn_perm((hi), (lo), 0x07060302u)
#define WQSCALE 0.18033688011112042f   // 0.125 * log2(e)
// LDS-only barrier: waits ds ops, leaves global prefetch loads in flight.
#define LBAR() do { asm volatile("s_waitcnt lgkmcnt(0)" ::: "memory"); \
                    __builtin_amdgcn_s_barrier(); } while (0)

// ---------------- Kernel 1: QKV projection (vectorized pack staging, R21 resubmit) ----------------
// R21: staging was 64 scalar f2bf + 64 scalar ds_write_b16 per thread (hipcc
// never vectorizes bf16 stores -- Common-mistake #2). Now: pack2bf pairs ->
// 2 ds_write_b128 per matrix per thread; V-transpose 1 ds_write_b64 per nt.
// LDS write instrs per thread: 80 -> 12. (R13 run was a container infra
// failure; kernel never executed. Byte-identical resubmit.)
__global__ __launch_bounds__(256) void qkv_proj(
    const float* __restrict__ x,
    const float* __restrict__ Wq, const float* __restrict__ Wk, const float* __restrict__ Wv,
    const float* __restrict__ Wo,
    ushort_t* __restrict__ q, ushort_t* __restrict__ k, ushort_t* __restrict__ vT,
    ushort_t* __restrict__ wob)
{
    __shared__ ushort_t Xs[64][72];
    __shared__ ushort_t Wqs[64][72], Wks[64][72], Wvs[64][72];
    int t = threadIdx.x;
    int bh = blockIdx.y, b = bh >> 4, h = bh & 15;
    int s0 = blockIdx.x * 64;
    {   // fused Wo fp32 -> bf16 (1024 blocks x 1024 elems), packed 8B store
        int woid = blockIdx.y * 32 + blockIdx.x;
        int i = woid * 1024 + t * 4;
        float4 f = *(const float4*)(Wo + i);
        unsigned w0 = pack2bf(f.x, f.y), w1 = pack2bf(f.z, f.w);
        uint2 u2; u2.x = w0; u2.y = w1;
        *(uint2*)(wob + i) = u2;
    }
    int i_ = t >> 2, d0_ = (t & 3) * 16;
    {   // stage x (64 s x 64 d) fp32 -> bf16, packed b128 stores
        const float* xp = x + ((size_t)(b * S + s0 + i_)) * E + h * D + d0_;
        unsigned xw[8];
        #pragma unroll
        for (int c = 0; c < 4; c++) {
            float4 f = *(const float4*)(xp + c * 4);
            xw[c * 2]     = pack2bf(f.x, f.y);
            xw[c * 2 + 1] = pack2bf(f.z, f.w);
        }
        *(bf16x8*)&Xs[i_][d0_]     = *(bf16x8*)&xw[0];
        *(bf16x8*)&Xs[i_][d0_ + 8] = *(bf16x8*)&xw[4];
    }
    {   // stage weights fp32 -> bf16 (Wq pre-scaled), packed b128 stores
        const float* wqp = Wq + i_ * 64 + d0_;
        const float* wkp = Wk + i_ * 64 + d0_;
        const float* wvp = Wv + i_ * 64 + d0_;
        unsigned ww[8];
        #pragma unroll
        for (int c = 0; c < 4; c++) {
            float4 f = *(const float4*)(wqp + c * 4);
            ww[c * 2]     = pack2bf(f.x * WQSCALE, f.y * WQSCALE);
            ww[c * 2 + 1] = pack2bf(f.z * WQSCALE, f.w * WQSCALE);
        }
        *(bf16x8*)&Wqs[i_][d0_]     = *(bf16x8*)&ww[0];
        *(bf16x8*)&Wqs[i_][d0_ + 8] = *(bf16x8*)&ww[4];
        #pragma unroll
        for (int c = 0; c < 4; c++) {
            float4 f = *(const float4*)(wkp + c * 4);
            ww[c * 2]     = pack2bf(f.x, f.y);
            ww[c * 2 + 1] = pack2bf(f.z, f.w);
        }
        *(bf16x8*)&Wks[i_][d0_]     = *(bf16x8*)&ww[0];
        *(bf16x8*)&Wks[i_][d0_ + 8] = *(bf16x8*)&ww[4];
        #pragma unroll
        for (int c = 0; c < 4; c++) {
            float4 f = *(const float4*)(wvp + c * 4);
            ww[c * 2]     = pack2bf(f.x, f.y);
            ww[c * 2 + 1] = pack2bf(f.z, f.w);
        }
        *(bf16x8*)&Wvs[i_][d0_]     = *(bf16x8*)&ww[0];
        *(bf16x8*)&Wvs[i_][d0_ + 8] = *(bf16x8*)&ww[4];
    }
    __syncthreads();
    int w = t >> 6, lane = t & 63, m = lane & 15, quad = lane >> 4;
    bf16x8 a0 = *(bf16x8*)&Xs[16 * w + m][quad * 8];
    bf16x8 a1 = *(bf16x8*)&Xs[16 * w + m][32 + quad * 8];
    f32x4 cq[4], ck[4], cv[4];
    #pragma unroll
    for (int nt = 0; nt < 4; nt++) { cq[nt] = (f32x4)0.f; ck[nt] = (f32x4)0.f; cv[nt] = (f32x4)0.f; }
    #pragma unroll
    for (int nt = 0; nt < 4; nt++) {
        bf16x8 b0, b1;
        b0 = *(bf16x8*)&Wqs[nt * 16 + m][quad * 8]; b1 = *(bf16x8*)&Wqs[nt * 16 + m][32 + quad * 8];
        cq[nt] = MFMA(a0, b0, cq[nt]); cq[nt] = MFMA(a1, b1, cq[nt]);
        b0 = *(bf16x8*)&Wks[nt * 16 + m][quad * 8]; b1 = *(bf16x8*)&Wks[nt * 16 + m][32 + quad * 8];
        ck[nt] = MFMA(a0, b0, ck[nt]); ck[nt] = MFMA(a1, b1, ck[nt]);
        b0 = *(bf16x8*)&Wvs[nt * 16 + m][quad * 8]; b1 = *(bf16x8*)&Wvs[nt * 16 + m][32 + quad * 8];
        cv[nt] = MFMA(a0, b0, cv[nt]); cv[nt] = MFMA(a1, b1, cv[nt]);
    }
    size_t base = (size_t)bh * S + s0;
    #pragma unroll
    for (int nt = 0; nt < 4; nt++)
        #pragma unroll
        for (int r = 0; r < 4; r++) {
            size_t idx = (base + 16 * w + quad * 4 + r) * D + nt * 16 + m;
            q[idx] = f2bf(cq[nt][r]);
            k[idx] = f2bf(ck[nt][r]);
        }
    __syncthreads();
    #pragma unroll
    for (int nt = 0; nt < 4; nt++) {   // v transpose: packed b64 store per nt
        unsigned v0 = pack2bf(cv[nt][0], cv[nt][1]);
        unsigned v1 = pack2bf(cv[nt][2], cv[nt][3]);
        uint2 u2; u2.x = v0; u2.y = v1;
        *(uint2*)&Wvs[nt * 16 + m][16 * w + quad * 4] = u2;
    }
    __syncthreads();
    {
        int d0 = t >> 2, sc = (t & 3) * 16;
        ushort_t* vp = vT + ((size_t)bh * D + d0) * S + s0 + sc;
        *(bf16x8*)(vp)     = *(bf16x8*)&Wvs[d0][sc];
        *(bf16x8*)(vp + 8) = *(bf16x8*)&Wvs[d0][sc + 8];
    }
}

// ---------------- Kernel 2: flash attention (exact R17: best measured 44.9 us) ----------------
// R19 lesson: allocator pins this kernel at 64 VGPR; extra live state spills.
// Do not hoist; do not restructure.
__global__ __launch_bounds__(512, 4) void flash_attn(
    const ushort_t* __restrict__ q, const ushort_t* __restrict__ k,
    const ushort_t* __restrict__ vT, ushort_t* __restrict__ ao)
{
    __shared__ ushort_t Ks[2][2][64][72];   // [grp][buf][s_local][d]
    __shared__ ushort_t Vt[2][2][64][72];   // [grp][buf][d][s_local]
    int t = threadIdx.x;
    int lin = blockIdx.x;                   // 512 blocks, 1-D
    int xcd = lin & 7, loc = lin >> 3;      // XCD round-robin %8
    int bh = xcd * 4 + (loc >> 4);          // 4 bh per XCD (2 MB K/V <= 4 MB L2)
    int q0 = (loc & 15) * 128;              // 16 q-tiles per bh
    int b = bh >> 4, h = bh & 15;
    int w = t >> 6, lane = t & 63, l31 = lane & 31, half = lane >> 5;
    int g = w >> 2, wq = w & 3;             // kv-split group, q-row wave
    int tg = t & 255;                       // staging id within group

    const ushort_t* qb = q + ((size_t)bh * S + q0) * D;
    const ushort_t* kb = k + (size_t)bh * S * D;
    const ushort_t* vb = vT + (size_t)bh * D * S;

    bf16x8 qf[4];
    {
        const ushort_t* qp = qb + (size_t)(wq * 32 + l31) * D + half * 8;
        #pragma unroll
        for (int c = 0; c < 4; c++) qf[c] = *(const bf16x8*)(qp + c * 16);
    }

    f32x16 o0 = (f32x16)0.f, o1 = (f32x16)0.f;
    float2 ls2 = make_float2(0.f, 0.f);

    int sr = tg >> 2, scc = (tg & 3) * 16;
    bf16x8 kp0, kp1, vp0, vp1;

    {
        int k00 = g * 64;
        const ushort_t* kp = kb + (size_t)(k00 + sr) * D + scc;
        const ushort_t* vp = vb + (size_t)sr * S + k00 + scc;
        kp0 = *(const bf16x8*)(kp);     kp1 = *(const bf16x8*)(kp + 8);
        vp0 = *(const bf16x8*)(vp);     vp1 = *(const bf16x8*)(vp + 8);
        *(bf16x8*)&Ks[g][0][sr][scc]     = kp0;
        *(bf16x8*)&Ks[g][0][sr][scc + 8] = kp1;
        *(bf16x8*)&Vt[g][0][sr][scc]     = vp0;
        *(bf16x8*)&Vt[g][0][sr][scc + 8] = vp1;
    }
    LBAR();
    {
        int k01 = (2 + g) * 64;
        const ushort_t* kp = kb + (size_t)(k01 + sr) * D + scc;
        const ushort_t* vp = vb + (size_t)sr * S + k01 + scc;
        kp0 = *(const bf16x8*)(kp);     kp1 = *(const bf16x8*)(kp + 8);
        vp0 = *(const bf16x8*)(vp);     vp1 = *(const bf16x8*)(vp + 8);
    }

    const int NJ = S / 128;   // 16 tiles per group (global tile = 2*jt + g)
    for (int jt = 0; jt < NJ; jt++) {
        int p = jt & 1;
        if (jt + 1 < NJ) {
            *(bf16x8*)&Ks[g][1 - p][sr][scc]     = kp0;
            *(bf16x8*)&Ks[g][1 - p][sr][scc + 8] = kp1;
            *(bf16x8*)&Vt[g][1 - p][sr][scc]     = vp0;
            *(bf16x8*)&Vt[g][1 - p][sr][scc + 8] = vp1;
        }
        if (jt + 2 < NJ) {
            int k0n = (2 * (jt + 2) + g) * 64;
            const ushort_t* kp = kb + (size_t)(k0n + sr) * D + scc;
            const ushort_t* vp = vb + (size_t)sr * S + k0n + scc;
            kp0 = *(const bf16x8*)(kp);     kp1 = *(const bf16x8*)(kp + 8);
            vp0 = *(const bf16x8*)(vp);     vp1 = *(const bf16x8*)(vp + 8);
        }

        union { unsigned u[4]; bf16x8 v; } pa[4];
        #pragma unroll
        for (int st = 0; st < 2; st++) {
            f32x16 e = (f32x16)0.f;
            __builtin_amdgcn_s_setprio(1);
            #pragma unroll
            for (int c = 0; c < 4; c++) {
                bf16x8 ka = *(bf16x8*)&Ks[g][p][st * 32 + l31][c * 16 + half * 8];
                e = MFMA32(ka, qf[c], e);
            }
            __builtin_amdgcn_s_setprio(0);
            unsigned pt[16];
            #pragma unroll
            for (int r = 0; r < 16; r += 2) {
                float pe0 = __builtin_amdgcn_exp2f(e[r]);
                float pe1 = __builtin_amdgcn_exp2f(e[r + 1]);
                ls2.x += pe0; ls2.y += pe1;
                pt[r]     = __float_as_uint(pe0);
                pt[r + 1] = __float_as_uint(pe1);
            }
            #pragma unroll
            for (int c2 = 0; c2 < 2; c2++) {
                int rb = c2 * 8;
                unsigned dA = PACKBF(pt[rb + 1], pt[rb + 0]);
                unsigned dB = PACKBF(pt[rb + 3], pt[rb + 2]);
                unsigned dC = PACKBF(pt[rb + 5], pt[rb + 4]);
                unsigned dD = PACKBF(pt[rb + 7], pt[rb + 6]);
                asm volatile("v_permlane32_swap_b32 %0, %1" : "+v"(dA), "+v"(dC));
                asm volatile("v_permlane32_swap_b32 %0, %1" : "+v"(dB), "+v"(dD));
                int kc = st * 2 + c2;
                pa[kc].u[0] = dA;
                pa[kc].u[1] = dB;
                pa[kc].u[2] = dC;
                pa[kc].u[3] = dD;
            }
        }

        __builtin_amdgcn_s_setprio(1);
        #pragma unroll
        for (int kc = 0; kc < 4; kc++) {
            bf16x8 vf0 = *(bf16x8*)&Vt[g][p][l31][kc * 16 + half * 8];
            bf16x8 vf1 = *(bf16x8*)&Vt[g][p][32 + l31][kc * 16 + half * 8];
            o0 = MFMA32(pa[kc].v, vf0, o0);
            o1 = MFMA32(pa[kc].v, vf1, o1);
        }
        __builtin_amdgcn_s_setprio(0);
        LBAR();   // LDS-only: prefetch loads NOT drained here
    }

    float lsum = ls2.x + ls2.y;
    float* cmb = (float*)&Ks[0][0][0][0];
    int slot = (wq * 64 + lane) * 33;
    if (g == 1) {
        #pragma unroll
        for (int r2 = 0; r2 < 16; r2++) { cmb[slot + r2] = o0[r2]; cmb[slot + 16 + r2] = o1[r2]; }
        cmb[slot + 32] = lsum;
    }
    __syncthreads();
    if (g == 0) {
        #pragma unroll
        for (int r2 = 0; r2 < 16; r2++) { o0[r2] += cmb[slot + r2]; o1[r2] += cmb[slot + 16 + r2]; }
        lsum += cmb[slot + 32];
        float lfull = lsum + __shfl_xor(lsum, 32, 64);
        float inv = 1.001953125f / lfull;
        #pragma unroll
        for (int reg = 0; reg < 16; reg++) {
            int qrow = (reg & 3) + 8 * (reg >> 2) + 4 * half;
            float li = __shfl(inv, qrow, 64);
            int srow = q0 + wq * 32 + qrow;
            size_t base2 = ((size_t)(b * S + srow)) * E + h * D + l31;
            ao[base2]      = f2bf(o0[reg] * li);
            ao[base2 + 32] = f2bf(o1[reg] * li);
        }
    }
}

// ---------------- Kernel 3: output projection (exact R17, LDS-staged A) ----------------
__global__ __launch_bounds__(512) void out_proj(
    const ushort_t* __restrict__ A, const ushort_t* __restrict__ Wob,
    const float* __restrict__ bo, float* __restrict__ Y)
{
    __shared__ ushort_t As[2][128][72];
    __shared__ ushort_t Ws[2][64][72];
    int t = threadIdx.x;
    int hwb = blockIdx.x;
    int swz = (hwb & 7) * 64 + (hwb >> 3);
    int n0 = (swz & 15) * 64, m0 = (swz >> 4) * 128;
    int w = t >> 6, lane = t & 63, m = lane & 15, quad = lane >> 4;
    f32x4 acc[4];
    #pragma unroll
    for (int nt = 0; nt < 4; nt++) acc[nt] = (f32x4)0.f;
    int ar = t >> 2, ac = (t & 3) * 16;
    int wr = t >> 3, wc = (t & 7) * 8;
    const ushort_t* apb = A + (size_t)(m0 + ar) * E + ac;
    const ushort_t* wpb = Wob + (size_t)(n0 + wr) * E + wc;
    bf16x8 arg[2], wrg;
    {
        *(bf16x8*)&As[0][ar][ac]     = *(const bf16x8*)(apb);
        *(bf16x8*)&As[0][ar][ac + 8] = *(const bf16x8*)(apb + 8);
        *(bf16x8*)&Ws[0][wr][wc]     = *(const bf16x8*)(wpb);
    }
    LBAR();
    {
        arg[0] = *(const bf16x8*)(apb + 64);
        arg[1] = *(const bf16x8*)(apb + 64 + 8);
        wrg    = *(const bf16x8*)(wpb + 64);
    }
    const int KT = E / 64;
    for (int ks = 0; ks < KT; ks++) {
        int p = ks & 1;
        if (ks + 1 < KT) {
            *(bf16x8*)&As[1 - p][ar][ac]     = arg[0];
            *(bf16x8*)&As[1 - p][ar][ac + 8] = arg[1];
            *(bf16x8*)&Ws[1 - p][wr][wc]     = wrg;
        }
        if (ks + 2 < KT) {
            int off = (ks + 2) * 64;
            arg[0] = *(const bf16x8*)(apb + off);
            arg[1] = *(const bf16x8*)(apb + off + 8);
            wrg    = *(const bf16x8*)(wpb + off);
        }
        #pragma unroll
        for (int h2 = 0; h2 < 2; h2++) {
            bf16x8 af = *(bf16x8*)&As[p][w * 16 + m][h2 * 32 + quad * 8];
            #pragma unroll
            for (int nt = 0; nt < 4; nt++) {
                bf16x8 bfr = *(bf16x8*)&Ws[p][nt * 16 + m][h2 * 32 + quad * 8];
                acc[nt] = MFMA(af, bfr, acc[nt]);
            }
        }
        LBAR();
    }
    #pragma unroll
    for (int nt = 0; nt < 4; nt++)
        #pragma unroll
        for (int r = 0; r < 4; r++) {
            int row = m0 + w * 16 + quad * 4 + r;
            int col = n0 + nt * 16 + m;
            Y[(size_t)row * E + col] = acc[nt][r] + bo[col];
        }
}

extern "C" void kernel_launch(void* const* d_in, const int* in_sizes, int n_in,
                              void* d_out, int out_size, void* d_ws, size_t ws_size,
                              hipStream_t stream)
{
    const float* x  = (const float*)d_in[0];
    const float* Wq = (const float*)d_in[1];
    const float* Wk = (const float*)d_in[2];
    const float* Wv = (const float*)d_in[3];
    const float* Wo = (const float*)d_in[4];
    const float* bo = (const float*)d_in[5];
    float* Y = (float*)d_out;

    const size_t n = (size_t)B * H * S * D;    // 4M elems
    ushort_t* qw  = (ushort_t*)d_ws;           // 8 MB
    ushort_t* kw  = qw + n;                    // 8 MB
    ushort_t* vTw = kw + n;                    // 8 MB  [bh][d][s]
    ushort_t* ao  = vTw + n;                   // 8 MB  (B,S,E)
    ushort_t* wob = ao + n;                    // 2 MB

    qkv_proj<<<dim3(S / 64, B * H), 256, 0, stream>>>(x, Wq, Wk, Wv, Wo, qw, kw, vTw, wob);
    flash_attn<<<dim3((S / 128) * B * H), 512, 0, stream>>>(qw, kw, vTw, ao);
    out_proj<<<dim3(512), 512, 0, stream>>>(ao, wob, bo, Y);
}